// Round 15
// baseline (524.306 us; speedup 1.0000x reference)
//
#include <hip/hip_runtime.h>

typedef __bf16 bf16;
typedef bf16 bf16x4 __attribute__((ext_vector_type(4)));
typedef bf16 bf16x8 __attribute__((ext_vector_type(8)));
typedef float f32x4 __attribute__((ext_vector_type(4)));

static constexpr int BATCH = 16;
static constexpr int SEQ   = 2048;  // N
static constexpr int DH    = 512;   // H (== M)
static constexpr int ROWS  = BATCH * SEQ;  // 32768

__device__ __forceinline__ f32x4 mfma16(bf16x8 a, bf16x8 b, f32x4 c) {
    return __builtin_amdgcn_mfma_f32_16x16x32_bf16(a, b, c, 0, 0, 0);
}

// async global->LDS, 16B per lane. dst must be wave-uniform base (HW adds lane*16).
__device__ __forceinline__ void gl_lds16(const void* g, void* l) {
    __builtin_amdgcn_global_load_lds((const __attribute__((address_space(1))) void*)g,
                                     (__attribute__((address_space(3))) void*)l, 16, 0, 0);
}

// ---------------- fp32 -> bf16 (vectorized) ----------------
__global__ void cvt_bf16_kernel(const float* __restrict__ in, bf16* __restrict__ out, int n4) {
    int i = blockIdx.x * blockDim.x + threadIdx.x;
    const int stride = gridDim.x * blockDim.x;
    for (; i < n4; i += stride) {
        f32x4 f = *reinterpret_cast<const f32x4*>(in + (size_t)i * 4);
        bf16x4 o;
        o[0] = (bf16)f[0]; o[1] = (bf16)f[1]; o[2] = (bf16)f[2]; o[3] = (bf16)f[3];
        *reinterpret_cast<bf16x4*>(out + (size_t)i * 4) = o;
    }
}

// -------- all 5 weights [K=512][N=512] fp32 -> [N][K] bf16, one launch --------
__global__ void cvt_wT5_kernel(const float* __restrict__ w0, const float* __restrict__ w1,
                               const float* __restrict__ w2, const float* __restrict__ w3,
                               const float* __restrict__ w4, bf16* __restrict__ out) {
    const int t = blockIdx.y;
    const float* in = (t == 0) ? w0 : (t == 1) ? w1 : (t == 2) ? w2 : (t == 3) ? w3 : w4;
    int idx = blockIdx.x * 256 + threadIdx.x;  // idx = n*512 + k
    int n = idx >> 9, k = idx & 511;
    out[t * 262144 + idx] = (bf16)in[k * 512 + n];
}

// ---------------- GEMM: Y = relu(X[R,512] @ W[512,512] + b), LDS staged ----
template <int OMODE>
__global__ __launch_bounds__(256, 2)
void gemm_relu_kernel(const bf16* __restrict__ X, const bf16* __restrict__ Wt,
                      const float* __restrict__ bias,
                      bf16* __restrict__ Y, bf16* __restrict__ Yt,
                      float* __restrict__ Yf)
{
    __shared__ bf16 Xl[2][128 * 64];
    __shared__ bf16 Wl[2][128 * 64];

    const int tid = threadIdx.x;
    const int lane = tid & 63, wid = tid >> 6;
    const int wr = wid >> 1, wc = wid & 1;
    const int r0 = blockIdx.x * 128;
    const int c0 = blockIdx.y * 128;
    const int lrow = lane & 15, lhi = lane >> 4;

    const int srow = tid >> 3;                // 0..31 within call
    const int skb  = (tid & 7) ^ (srow & 7);  // pre-swizzled source block
    const int sdst = wid * 512;               // this wave's 1KB chunk

    auto stage = [&](int buf, int kc) {
        const bf16* xs = X + (size_t)r0 * 512 + kc * 64;
        const bf16* ws = Wt + (size_t)c0 * 512 + kc * 64;
        #pragma unroll
        for (int c = 0; c < 4; ++c) {
            const int row = c * 32 + srow;
            gl_lds16(xs + (size_t)row * 512 + skb * 8, &Xl[buf][c * 2048 + sdst]);
        }
        #pragma unroll
        for (int c = 0; c < 4; ++c) {
            const int row = c * 32 + srow;
            gl_lds16(ws + (size_t)row * 512 + skb * 8, &Wl[buf][c * 2048 + sdst]);
        }
    };

    f32x4 acc[4][4] = {};

    stage(0, 0);
    __syncthreads();

    for (int t = 0; t < 8; ++t) {
        const int buf = t & 1;
        if (t + 1 < 8) stage(buf ^ 1, t + 1);
        #pragma unroll
        for (int kk = 0; kk < 2; ++kk) {
            bf16x8 af[4], bfr[4];
            const int kb = kk * 4 + lhi;
            #pragma unroll
            for (int tt = 0; tt < 4; ++tt) {
                const int ra = wr * 64 + tt * 16 + lrow;
                af[tt] = *reinterpret_cast<const bf16x8*>(&Xl[buf][ra * 64 + ((kb ^ (ra & 7)) * 8)]);
            }
            #pragma unroll
            for (int tt = 0; tt < 4; ++tt) {
                const int rb = wc * 64 + tt * 16 + lrow;
                bfr[tt] = *reinterpret_cast<const bf16x8*>(&Wl[buf][rb * 64 + ((kb ^ (rb & 7)) * 8)]);
            }
            #pragma unroll
            for (int i = 0; i < 4; ++i)
                #pragma unroll
                for (int j = 0; j < 4; ++j)
                    acc[i][j] = mfma16(af[i], bfr[j], acc[i][j]);
        }
        __syncthreads();
    }

    #pragma unroll
    for (int i = 0; i < 4; ++i) {
        #pragma unroll
        for (int j = 0; j < 4; ++j) {
            const int col = c0 + wc * 64 + j * 16 + lrow;
            const float bb = bias[col];
            #pragma unroll
            for (int rg = 0; rg < 4; ++rg) {
                const int r = r0 + wr * 64 + i * 16 + lhi * 4 + rg;
                float y = acc[i][j][rg] + bb;
                y = y > 0.f ? y : 0.f;
                if (OMODE == 2) {
                    Yf[(size_t)r * 512 + col] = y;
                } else {
                    Y[(size_t)r * 512 + col] = (bf16)y;
                    if (OMODE == 1) {
                        const int bi = r >> 11, nn = r & 2047;
                        Yt[((size_t)bi * 512 + col) * 2048 + nn] = (bf16)y;
                    }
                }
            }
        }
    }
}

// ---------------- fused attention ----------------
// scores = (Q K^T) * (-A); att = softmax(scores); O = att @ V + V  (bf16 out)
// max==0 softmax (R12/R13-validated): q,k>=0 and A in [0,1) => scores<=0 =>
// p = exp(x) directly, l accumulated per-lane, reduced once at epilogue.
// R13 geometry: 8 waves, wave (wr=wid>>1: 16 q-rows, wc=wid&1: 32-col strip),
// KVBLK=64, 32 iters. NEW in R15: A is staged into LDS double-buffered via
// global_load_lds one iteration ahead (zero VGPR cost, HBM latency hidden
// under a full iteration) — removes the last register-pressure-sunk in-loop
// VMEM besides Vt; Vt loads moved inside PV (regs live only during PV).
// K single-buffered (64KB), staged after B1 (R14-validated; WAR-safe since
// B1's lgkm(0) retires all K reads; completion via in-order vmcnt: vf loads
// issued after stage, waited in PV; B2 publishes). LDS: 64+32+9+0.5=105.6KB.
__global__ __launch_bounds__(512, 1)
void attn_kernel(const bf16* __restrict__ Q, const bf16* __restrict__ K,
                 const bf16* __restrict__ Vt, const bf16* __restrict__ V,
                 const float* __restrict__ A, bf16* __restrict__ O)
{
    __shared__ bf16 K_lds[64 * 512];      // 64KB, XOR-swizzled rows, single buffer
    __shared__ float A_lds[2][64 * 64];   // 2 x 16KB, row-linear (64 fp32/row)
    __shared__ bf16 P_lds[64 * 72];       // 9KB, stride 72 (144B rows)
    __shared__ float sump_lds[2][64];     // per-strip l partials (epilogue only)

    const int tid = threadIdx.x;
    const int lane = tid & 63, wid = tid >> 6;
    const int wr = wid >> 1, wc = wid & 1;
    const int lrow = lane & 15, lhi = lane >> 4;

    // XCD x handles batches {2x, 2x+1}
    const int id = blockIdx.x;
    const int xcd = id & 7, j = id >> 3;
    const int bb = 2 * xcd + (j >> 5);
    const int n0 = (j & 31) * 64;
    const int srow_base = wr * 16 + lhi * 4;

    const bf16* Kbase  = K + (size_t)bb * SEQ * DH;
    const bf16* Vtbase = Vt + (size_t)bb * DH * SEQ;
    const float* Abase = A + ((size_t)bb * SEQ + n0) * SEQ;  // 64 q-rows of A

    // A-tile stage: 16KB = 64 rows x 64 fp32. 2 calls x 8 waves x 64 lanes x 16B.
    // Call c: wave-uniform LDS base row = wid*8 + c*4; HW lane offset l*16B
    // maps lane -> (row = base+ (l>>4), col = (l&15)*4) matching global addr.
    auto stageA = [&](int ab, int m0n) {
        #pragma unroll
        for (int c = 0; c < 2; ++c) {
            const int row = wid * 8 + c * 4 + (lane >> 4);
            gl_lds16(Abase + (size_t)row * SEQ + m0n + (lane & 15) * 4,
                     &A_lds[ab][(wid * 8 + c * 4) * 64]);
        }
    };

    // prologue: stage K[0] (8 rows/wave) + A[0]
    #pragma unroll
    for (int c = 0; c < 8; ++c) {
        const int row = wid * 8 + c;
        gl_lds16(Kbase + (size_t)row * DH + ((lane ^ (row & 7)) * 8), &K_lds[row * 512]);
    }
    stageA(0, 0);

    // Q resident: rows n0 + wr*16 + lrow (wc pair loads same rows). 64 VGPR.
    bf16x8 qf[16];
    {
        const bf16* qp = Q + (size_t)(bb * SEQ + n0 + wr * 16 + lrow) * DH + lhi * 8;
        #pragma unroll
        for (int kk = 0; kk < 16; ++kk)
            qf[kk] = *reinterpret_cast<const bf16x8*>(qp + kk * 32);
    }

    float l_part[4] = {};      // per-lane denominator partials (rows srow_base+rg)
    f32x4 acc[4][4] = {};      // [q-row-tile][h-tile of this wave's 64-col slice]

    __syncthreads();  // K[0] + A[0] drained + published

    int abuf = 0;
    for (int it = 0; it < 32; ++it) {
        const int m0 = it * 64;

        // stage A[it+1] -> other A buffer (completes via PV's vf waits; B2 publishes;
        // consumed in next iter's exp phase). Zero VGPR cost.
        if (it + 1 < 32) stageA(abuf ^ 1, m0 + 64);

        // ---- QK^T: S[16 x 32-col strip] from K_lds (32 rows per wave) ----
        f32x4 s0 = {}, s1 = {};
        {
            const int kr0 = wc * 32 + lrow, kr1 = kr0 + 16;
            #pragma unroll
            for (int kk = 0; kk < 16; ++kk) {
                const int ks = kk * 4 + lhi;
                bf16x8 k0 = *reinterpret_cast<const bf16x8*>(
                    &K_lds[kr0 * 512 + ((ks ^ (kr0 & 7)) * 8)]);
                bf16x8 k1 = *reinterpret_cast<const bf16x8*>(
                    &K_lds[kr1 * 512 + ((ks ^ (kr1 & 7)) * 8)]);
                s0 = mfma16(qf[kk], k0, s0);
                s1 = mfma16(qf[kk], k1, s1);
            }
        }

        // ---- p = exp(score * -A) (max==0); A from LDS; P -> LDS ----
        #pragma unroll
        for (int rg = 0; rg < 4; ++rg) {
            const int row = srow_base + rg;
            const float a0 = A_lds[abuf][row * 64 + wc * 32 + lrow];
            const float a1 = A_lds[abuf][row * 64 + wc * 32 + 16 + lrow];
            const float p0 = __expf(s0[rg] * (-a0));
            const float p1 = __expf(s1[rg] * (-a1));
            const int c0i = wc * 32 + lrow;
            P_lds[row * 72 + c0i]      = (bf16)p0;
            P_lds[row * 72 + c0i + 16] = (bf16)p1;
            l_part[rg] += p0 + p1;
        }

        // B1: lgkm-only — P writes + K/A reads retired; VMEM stays in flight
        asm volatile("s_waitcnt lgkmcnt(0)" ::: "memory");
        __builtin_amdgcn_s_barrier();
        __builtin_amdgcn_sched_barrier(0);

        // stage K[it+1] into the SAME buffer (WAR-safe: all K reads retired at
        // B1). Completion: vf loads in PV are issued AFTER these; PV's vf wait
        // (in-order vmcnt) forces stage completion; B2 publishes block-wide.
        if (it + 1 < 32) {
            #pragma unroll
            for (int c = 0; c < 8; ++c) {
                const int row = wid * 8 + c;
                gl_lds16(Kbase + (size_t)(m0 + 64 + row) * DH + ((lane ^ (row & 7)) * 8),
                         &K_lds[row * 512]);
            }
        }

        // ---- PV: P (LDS) x Vt (regs, loaded here — live only during PV) ----
        {
            const bf16* vp = Vtbase + (size_t)(wid * 64 + lrow) * SEQ + m0 + lhi * 8;
            bf16x8 vf[4][2];
            #pragma unroll
            for (int ht = 0; ht < 4; ++ht)
                #pragma unroll
                for (int kc = 0; kc < 2; ++kc)
                    vf[ht][kc] = *reinterpret_cast<const bf16x8*>(
                        vp + (size_t)(ht * 16) * SEQ + kc * 32);
            #pragma unroll
            for (int t = 0; t < 4; ++t) {
                bf16x8 pf[2];
                #pragma unroll
                for (int kc = 0; kc < 2; ++kc)
                    pf[kc] = *reinterpret_cast<const bf16x8*>(
                        &P_lds[(t * 16 + lrow) * 72 + kc * 32 + lhi * 8]);
                #pragma unroll
                for (int ht = 0; ht < 4; ++ht)
                    #pragma unroll
                    for (int kc = 0; kc < 2; ++kc)
                        acc[t][ht] = mfma16(pf[kc], vf[ht][kc], acc[t][ht]);
            }
        }

        // B2: lgkm-only — P reads retired (WAR); K[it+1]/A[it+1] stages complete
        // per-wave (via vf in-order waits) -> published block-wide.
        asm volatile("s_waitcnt lgkmcnt(0)" ::: "memory");
        __builtin_amdgcn_s_barrier();
        __builtin_amdgcn_sched_barrier(0);

        abuf ^= 1;
    }

    // ---- epilogue: reduce l over the 16 lrow lanes per strip, combine strips ----
    #pragma unroll
    for (int rg = 0; rg < 4; ++rg) {
        float sv = l_part[rg];
        sv += __shfl_xor(sv, 1);
        sv += __shfl_xor(sv, 2);
        sv += __shfl_xor(sv, 4);
        sv += __shfl_xor(sv, 8);
        if (lrow == 0) sump_lds[wc][srow_base + rg] = sv;
    }
    __syncthreads();

    // ---- /l, +V, store ----
    #pragma unroll
    for (int t = 0; t < 4; ++t) {
        #pragma unroll
        for (int rg = 0; rg < 4; ++rg) {
            const int row = t * 16 + lhi * 4 + rg;
            const float inv = 1.f / (sump_lds[0][row] + sump_lds[1][row]);
            const size_t rbase = (size_t)(bb * SEQ + n0 + row) * DH;
            #pragma unroll
            for (int ht = 0; ht < 4; ++ht) {
                const int col = wid * 64 + ht * 16 + lrow;
                const float vv = (float)V[rbase + col];
                O[rbase + col] = (bf16)(acc[t][ht][rg] * inv + vv);
            }
        }
    }
}

extern "C" void kernel_launch(void* const* d_in, const int* in_sizes, int n_in,
                              void* d_out, int out_size, void* d_ws, size_t ws_size,
                              hipStream_t stream) {
    const float* A    = (const float*)d_in[0];
    const float* h    = (const float*)d_in[1];
    const float* Wv1  = (const float*)d_in[2];
    const float* bv1  = (const float*)d_in[3];
    const float* Wv2  = (const float*)d_in[4];
    const float* bv2  = (const float*)d_in[5];
    const float* Wk   = (const float*)d_in[6];   // NOTE: Wk before Wq in dict order
    const float* bk   = (const float*)d_in[7];
    const float* Wq   = (const float*)d_in[8];
    const float* bq   = (const float*)d_in[9];
    const float* Wout = (const float*)d_in[10];
    const float* bout = (const float*)d_in[11];
    float* out = (float*)d_out;

    char* ws = (char*)d_ws;
    const size_t SZ = (size_t)ROWS * 512 * sizeof(bf16);  // 33.5 MB
    bf16* hb   = (bf16*)(ws + 0 * SZ);  // h in bf16; later reused as attention output
    bf16* tq   = (bf16*)(ws + 1 * SZ);  // t = relu(h@Wv1), later overwritten with q
    bf16* kb   = (bf16*)(ws + 2 * SZ);
    bf16* vb   = (bf16*)(ws + 3 * SZ);
    bf16* vtb  = (bf16*)(ws + 4 * SZ);  // v transposed: [B][H][N]
    bf16* wbase = (bf16*)(ws + 5 * SZ); // 5 x 512KB bf16 weights
    bf16* Wv1t  = wbase + 0 * 262144;
    bf16* Wv2t  = wbase + 1 * 262144;
    bf16* Wqt   = wbase + 2 * 262144;
    bf16* Wkt   = wbase + 3 * 262144;
    bf16* Woutt = wbase + 4 * 262144;
    bf16* ob = hb;  // attention output aliases hb (hb dead after k projection)

    cvt_bf16_kernel<<<4096, 256, 0, stream>>>(h, hb, ROWS * 512 / 4);
    cvt_wT5_kernel<<<dim3(1024, 5), 256, 0, stream>>>(Wv1, Wv2, Wq, Wk, Wout, wbase);

    dim3 gg(ROWS / 128, 512 / 128);  // (256, 4)
    gemm_relu_kernel<0><<<gg, 256, 0, stream>>>(hb, Wv1t, bv1, tq, nullptr, nullptr);  // t
    gemm_relu_kernel<1><<<gg, 256, 0, stream>>>(tq, Wv2t, bv2, vb, vtb, nullptr);      // v + vT
    gemm_relu_kernel<0><<<gg, 256, 0, stream>>>(hb, Wqt, bq, tq, nullptr, nullptr);    // q (over t)
    gemm_relu_kernel<0><<<gg, 256, 0, stream>>>(hb, Wkt, bk, kb, nullptr, nullptr);    // k

    attn_kernel<<<dim3(512), 512, 0, stream>>>(tq, kb, vtb, vb, A, ob);

    gemm_relu_kernel<2><<<gg, 256, 0, stream>>>(ob, Woutt, bout, nullptr, nullptr, out);
}